// Round 1
// baseline (15888.805 us; speedup 1.0000x reference)
//
#include <hip/hip_runtime.h>
#include <math.h>

#define DT 0.01f
constexpr int T = 512, B = 128, I = 256, H = 1024, O = 256;
constexpr int KC = 128;   // K-chunk staged in LDS
constexpr int BT = 32;    // rows per WG tile
constexpr int CT = 16;    // cols per WG tile

// workspace layout (float offsets)
constexpr size_t OFF_HU0  = 0;
constexpr size_t OFF_HU1  = OFF_HU0  + (size_t)B * H;
constexpr size_t OFF_HV   = OFF_HU1  + (size_t)B * H;
constexpr size_t OFF_OU   = OFF_HV   + (size_t)B * H;
constexpr size_t OFF_OSUM = OFF_OU   + (size_t)B * H;
constexpr size_t OFF_CB   = OFF_OSUM + (size_t)B * H;  // damping b
constexpr size_t OFF_CO2  = OFF_CB   + H;              // omega^2
constexpr size_t OFF_CAL  = OFF_CO2  + H;              // alpha
constexpr size_t OFF_CG   = OFF_CAL  + H;              // gain

__global__ __launch_bounds__(256)
void init_kernel(float* __restrict__ ws, const float* __restrict__ omega,
                 const float* __restrict__ b_offset, const float* __restrict__ tau_mem,
                 const float* __restrict__ gain) {
    size_t tid = (size_t)blockIdx.x * blockDim.x + threadIdx.x;
    size_t stride = (size_t)gridDim.x * blockDim.x;
    for (size_t i = tid; i < OFF_CB; i += stride) ws[i] = 0.0f;
    if (tid < H) {
        float om  = fabsf(omega[tid]);
        float om2 = om * om;
        ws[OFF_CO2 + tid] = om2;
        ws[OFF_CB  + tid] = om2 * 0.005f + fabsf(b_offset[tid]);
        ws[OFF_CAL + tid] = expf(-1.0f / fabsf(tau_mem[tid]));
        ws[OFF_CG  + tid] = gain[tid];
    }
}

// One timestep. Computes (for this WG's 32x16 tile):
//   p = hu_in @ W_o^T            -> ou = ou*alpha + p*(1-alpha); ou_sum += ou
//   in_sum = [x_s, hu_in] @ W_h^T -> harmonic update -> hu_out, hv   (PHASE_B only)
template <bool PHASE_B>
__global__ __launch_bounds__(256)
void step_kernel(const float* __restrict__ xs,     // [B][I] for this step (PHASE_B)
                 const float* __restrict__ hu_in,  // [B][H]
                 float* __restrict__ hu_out,       // [B][H] (PHASE_B)
                 float* __restrict__ hv,           // [B][H] (PHASE_B)
                 float* __restrict__ ou,           // [B][H]
                 float* __restrict__ ou_sum,       // [B][H]
                 const float* __restrict__ W_h,    // [H][I+H]
                 const float* __restrict__ W_o,    // [H][H]
                 const float* __restrict__ ws) {   // coef base
    __shared__ float act[BT][KC + 4];
    __shared__ float wA[CT][KC + 4];   // W_o chunk
    __shared__ float wB[CT][KC + 4];   // W_h chunk

    // XCD-aware swizzle: col-groups [8x, 8x+8) pinned to XCD x (weight slice ~1.15MB L2-resident)
    int wg  = blockIdx.x;
    int xcd = wg & 7;
    int idx = wg >> 3;
    int cg  = xcd * 8 + (idx >> 2);   // 0..63
    int bt  = idx & 3;                // 0..3
    int row0 = bt * BT, col0 = cg * CT;
    int tid = threadIdx.x;
    int c  = tid & 15;     // col within tile
    int rr = tid >> 4;     // 0..15 -> rows rr and rr+16

    float4 accP0 = {0,0,0,0}, accP1 = {0,0,0,0};
    float4 accS0 = {0,0,0,0}, accS1 = {0,0,0,0};

    // ---- K over hidden part (shared by both GEMMs) ----
    for (int kc = 0; kc < H / KC; ++kc) {
        int k0 = kc * KC;
        for (int i = tid; i < BT * (KC / 4); i += 256) {
            int r = i >> 5, c4 = (i & 31) * 4;
            *(float4*)&act[r][c4] = *(const float4*)&hu_in[(size_t)(row0 + r) * H + k0 + c4];
        }
        for (int i = tid; i < CT * (KC / 4); i += 256) {
            int r = i >> 5, c4 = (i & 31) * 4;
            *(float4*)&wA[r][c4] = *(const float4*)&W_o[(size_t)(col0 + r) * H + k0 + c4];
            if (PHASE_B)
                *(float4*)&wB[r][c4] = *(const float4*)&W_h[(size_t)(col0 + r) * (I + H) + I + k0 + c4];
        }
        __syncthreads();
        #pragma unroll
        for (int k4 = 0; k4 < KC / 4; ++k4) {
            float4 a0 = *(const float4*)&act[rr][k4 * 4];
            float4 a1 = *(const float4*)&act[rr + 16][k4 * 4];
            float4 w0 = *(const float4*)&wA[c][k4 * 4];
            accP0.x = fmaf(a0.x, w0.x, accP0.x); accP0.y = fmaf(a0.y, w0.y, accP0.y);
            accP0.z = fmaf(a0.z, w0.z, accP0.z); accP0.w = fmaf(a0.w, w0.w, accP0.w);
            accP1.x = fmaf(a1.x, w0.x, accP1.x); accP1.y = fmaf(a1.y, w0.y, accP1.y);
            accP1.z = fmaf(a1.z, w0.z, accP1.z); accP1.w = fmaf(a1.w, w0.w, accP1.w);
            if (PHASE_B) {
                float4 w1 = *(const float4*)&wB[c][k4 * 4];
                accS0.x = fmaf(a0.x, w1.x, accS0.x); accS0.y = fmaf(a0.y, w1.y, accS0.y);
                accS0.z = fmaf(a0.z, w1.z, accS0.z); accS0.w = fmaf(a0.w, w1.w, accS0.w);
                accS1.x = fmaf(a1.x, w1.x, accS1.x); accS1.y = fmaf(a1.y, w1.y, accS1.y);
                accS1.z = fmaf(a1.z, w1.z, accS1.z); accS1.w = fmaf(a1.w, w1.w, accS1.w);
            }
        }
        __syncthreads();
    }

    // ---- K over input part (in_sum only) ----
    if (PHASE_B) {
        for (int kc = 0; kc < I / KC; ++kc) {
            int k0 = kc * KC;
            for (int i = tid; i < BT * (KC / 4); i += 256) {
                int r = i >> 5, c4 = (i & 31) * 4;
                *(float4*)&act[r][c4] = *(const float4*)&xs[(size_t)(row0 + r) * I + k0 + c4];
            }
            for (int i = tid; i < CT * (KC / 4); i += 256) {
                int r = i >> 5, c4 = (i & 31) * 4;
                *(float4*)&wB[r][c4] = *(const float4*)&W_h[(size_t)(col0 + r) * (I + H) + k0 + c4];
            }
            __syncthreads();
            #pragma unroll
            for (int k4 = 0; k4 < KC / 4; ++k4) {
                float4 a0 = *(const float4*)&act[rr][k4 * 4];
                float4 a1 = *(const float4*)&act[rr + 16][k4 * 4];
                float4 w1 = *(const float4*)&wB[c][k4 * 4];
                accS0.x = fmaf(a0.x, w1.x, accS0.x); accS0.y = fmaf(a0.y, w1.y, accS0.y);
                accS0.z = fmaf(a0.z, w1.z, accS0.z); accS0.w = fmaf(a0.w, w1.w, accS0.w);
                accS1.x = fmaf(a1.x, w1.x, accS1.x); accS1.y = fmaf(a1.y, w1.y, accS1.y);
                accS1.z = fmaf(a1.z, w1.z, accS1.z); accS1.w = fmaf(a1.w, w1.w, accS1.w);
            }
            __syncthreads();
        }
    }

    float p[2], s[2];
    p[0] = (accP0.x + accP0.y) + (accP0.z + accP0.w);
    p[1] = (accP1.x + accP1.y) + (accP1.z + accP1.w);
    s[0] = (accS0.x + accS0.y) + (accS0.z + accS0.w);
    s[1] = (accS1.x + accS1.y) + (accS1.z + accS1.w);

    int gcol = col0 + c;
    float cb   = ws[OFF_CB  + gcol];
    float co2  = ws[OFF_CO2 + gcol];
    float cal  = ws[OFF_CAL + gcol];
    float cgn  = ws[OFF_CG  + gcol];

    #pragma unroll
    for (int j = 0; j < 2; ++j) {
        int grow = row0 + rr + j * 16;
        size_t ix = (size_t)grow * H + gcol;
        // LI update of the *previous* step's hu (hu_in = hu^s): ou^s
        float oun = ou[ix] * cal + p[j] * (1.0f - cal);
        ou[ix] = oun;
        ou_sum[ix] += oun;
        if (PHASE_B) {
            float hu_old = hu_in[ix];
            float hvn = hv[ix] + hu_old * DT;
            float hun = hu_old + s[j] * DT - cb * hu_old * (2.0f * DT) - co2 * hvn * DT;
            hun *= cgn;
            hv[ix] = hvn;
            hu_out[ix] = hun;
        }
    }
}

// acc = ou_sum @ W_out^T + T*b_out
__global__ __launch_bounds__(256)
void readout_kernel(const float* __restrict__ ou_sum, const float* __restrict__ W_out,
                    const float* __restrict__ b_out, float* __restrict__ out) {
    __shared__ float act[BT][KC + 4];
    __shared__ float w[CT][KC + 4];
    int wg = blockIdx.x;           // 64 WGs: 4 row tiles x 16 col groups
    int bt = wg & 3, cg = wg >> 2;
    int row0 = bt * BT, col0 = cg * CT;
    int tid = threadIdx.x;
    int c = tid & 15, rr = tid >> 4;

    float4 acc0 = {0,0,0,0}, acc1 = {0,0,0,0};
    for (int kc = 0; kc < H / KC; ++kc) {
        int k0 = kc * KC;
        for (int i = tid; i < BT * (KC / 4); i += 256) {
            int r = i >> 5, c4 = (i & 31) * 4;
            *(float4*)&act[r][c4] = *(const float4*)&ou_sum[(size_t)(row0 + r) * H + k0 + c4];
        }
        for (int i = tid; i < CT * (KC / 4); i += 256) {
            int r = i >> 5, c4 = (i & 31) * 4;
            *(float4*)&w[r][c4] = *(const float4*)&W_out[(size_t)(col0 + r) * H + k0 + c4];
        }
        __syncthreads();
        #pragma unroll
        for (int k4 = 0; k4 < KC / 4; ++k4) {
            float4 a0 = *(const float4*)&act[rr][k4 * 4];
            float4 a1 = *(const float4*)&act[rr + 16][k4 * 4];
            float4 w0 = *(const float4*)&w[c][k4 * 4];
            acc0.x = fmaf(a0.x, w0.x, acc0.x); acc0.y = fmaf(a0.y, w0.y, acc0.y);
            acc0.z = fmaf(a0.z, w0.z, acc0.z); acc0.w = fmaf(a0.w, w0.w, acc0.w);
            acc1.x = fmaf(a1.x, w0.x, acc1.x); acc1.y = fmaf(a1.y, w0.y, acc1.y);
            acc1.z = fmaf(a1.z, w0.z, acc1.z); acc1.w = fmaf(a1.w, w0.w, acc1.w);
        }
        __syncthreads();
    }
    float v0 = (acc0.x + acc0.y) + (acc0.z + acc0.w);
    float v1 = (acc1.x + acc1.y) + (acc1.z + acc1.w);
    int gcol = col0 + c;
    float bo = b_out[gcol] * (float)T;
    out[(size_t)(row0 + rr) * O + gcol] = v0 + bo;
    out[(size_t)(row0 + rr + 16) * O + gcol] = v1 + bo;
}

extern "C" void kernel_launch(void* const* d_in, const int* in_sizes, int n_in,
                              void* d_out, int out_size, void* d_ws, size_t ws_size,
                              hipStream_t stream) {
    const float* x        = (const float*)d_in[0];
    const float* W_h      = (const float*)d_in[1];
    const float* gain     = (const float*)d_in[2];
    const float* omega    = (const float*)d_in[3];
    const float* b_offset = (const float*)d_in[4];
    const float* W_o      = (const float*)d_in[5];
    const float* tau_mem  = (const float*)d_in[6];
    const float* W_out    = (const float*)d_in[7];
    const float* b_out    = (const float*)d_in[8];
    float* ws  = (float*)d_ws;
    float* out = (float*)d_out;

    init_kernel<<<256, 256, 0, stream>>>(ws, omega, b_offset, tau_mem, gain);

    float* hu[2] = {ws + OFF_HU0, ws + OFF_HU1};
    for (int s = 0; s < T; ++s) {
        step_kernel<true><<<256, 256, 0, stream>>>(
            x + (size_t)s * B * I, hu[s & 1], hu[(s + 1) & 1],
            ws + OFF_HV, ws + OFF_OU, ws + OFF_OSUM, W_h, W_o, ws);
    }
    // final LI update with hu^T (T even -> lives in hu[0])
    step_kernel<false><<<256, 256, 0, stream>>>(
        nullptr, hu[T & 1], nullptr,
        ws + OFF_HV, ws + OFF_OU, ws + OFF_OSUM, W_h, W_o, ws);

    readout_kernel<<<64, 256, 0, stream>>>(ws + OFF_OSUM, W_out, b_out, out);
}